// Round 10
// baseline (224.596 us; speedup 1.0000x reference)
//
#include <hip/hip_runtime.h>
#include <math.h>

// Problem: B=8, N=192, C=16.
// out[b,i,j,k] = argmax(t0[b,i,:]) * argmax(t1[b,j,:]) * argmax(t2[b,k,:])
//                * (i!=j && i!=k && j!=k)
// Reference .astype(jnp.int64) under default JAX (x64 disabled) -> int32.
// Harness reads d_out as int32 (round-8 absmax 1.166e9 == float-bits-as-int
// signature). So we write int32.
// Output: 8*192^3 = 56,623,104 int32 (~226.5 MB) -> pure write-BW bound.

#define B 8
#define N 192
#define C 16
#define ROWS (B * N)          // 1536 rows per tensor
#define K4 (N / 4)            // 48 int4 per k-row

typedef int   v4i __attribute__((ext_vector_type(4)));
typedef float v4f __attribute__((ext_vector_type(4)));

// Phase 1: argmax of each 16-float row for all three tensors.
// 3*1536 = 4608 rows total. First-occurrence tie-break (strict >).
__global__ void argmax_rows(const float* __restrict__ t0,
                            const float* __restrict__ t1,
                            const float* __restrict__ t2,
                            int* __restrict__ p /* 3*ROWS ints */) {
    int idx = blockIdx.x * blockDim.x + threadIdx.x;
    if (idx >= 3 * ROWS) return;
    int which = idx / ROWS;
    int row   = idx - which * ROWS;
    const float* src = (which == 0) ? t0 : (which == 1) ? t1 : t2;
    const v4f* r = reinterpret_cast<const v4f*>(src + (size_t)row * C);
    float best = -INFINITY;
    int bi = 0;
#pragma unroll
    for (int q = 0; q < 4; ++q) {
        v4f v = r[q];
#pragma unroll
        for (int c = 0; c < 4; ++c) {
            if (v[c] > best) { best = v[c]; bi = q * 4 + c; }
        }
    }
    p[idx] = bi;
}

// Phase 2: write the masked outer product. One v4i (4 k-values) per thread.
// grid = (36, 192, 8): x covers j*k (192*48 vec4 = 9216 = 36*256), y=i, z=b.
__global__ __launch_bounds__(256) void joint_candidate(
        const int* __restrict__ p, v4i* __restrict__ out) {
    const int* p0 = p;                 // [B*N] argmax(t0)
    const int* p1 = p + ROWS;          // argmax(t1)
    const int* p2 = p + 2 * ROWS;      // argmax(t2)

    const int b = blockIdx.z;
    const int i = blockIdx.y;
    const int t = blockIdx.x * 256 + threadIdx.x;   // 0..9215
    const int j  = t / K4;                          // const divide -> magic mul
    const int k4 = t - j * K4;
    const int k0 = k4 * 4;

    const int vij = p0[b * N + i] * p1[b * N + j];  // b,i block-uniform
    const v4i vk = reinterpret_cast<const v4i*>(p2 + b * N)[k4];

    const bool inej = (i != j);
    v4i o;
    o.x = (inej && i != k0     && j != k0    ) ? vij * vk.x : 0;
    o.y = (inej && i != k0 + 1 && j != k0 + 1) ? vij * vk.y : 0;
    o.z = (inej && i != k0 + 2 && j != k0 + 2) ? vij * vk.z : 0;
    o.w = (inej && i != k0 + 3 && j != k0 + 3) ? vij * vk.w : 0;

    const size_t off = ((size_t)(b * N + i) * N + j) * K4 + k4;
    // Write-once, never re-read: bypass cache dirtying with nontemporal store.
    __builtin_nontemporal_store(o, &out[off]);
}

extern "C" void kernel_launch(void* const* d_in, const int* in_sizes, int n_in,
                              void* d_out, int out_size, void* d_ws, size_t ws_size,
                              hipStream_t stream) {
    const float* t0 = (const float*)d_in[0];
    const float* t1 = (const float*)d_in[1];
    const float* t2 = (const float*)d_in[2];
    int* p = (int*)d_ws;               // 3*1536 ints = 18 KB scratch

    argmax_rows<<<(3 * ROWS + 255) / 256, 256, 0, stream>>>(t0, t1, t2, p);
    joint_candidate<<<dim3(36, N, B), 256, 0, stream>>>(p, (v4i*)d_out);
}